// Round 7
// baseline (3540.300 us; speedup 1.0000x reference)
//
#include <hip/hip_runtime.h>
#include <math.h>

// Problem constants (TransformerController)
#define B_  32
#define S_  512
#define T_  180
#define D_  512
#define F_  2048
#define L_  6
#define H_  8
#define DH_ 64

typedef unsigned short u16;
typedef __attribute__((ext_vector_type(8))) short short8;   // 8 x bf16
typedef __attribute__((ext_vector_type(4))) float floatx4;  // MFMA acc

__device__ __forceinline__ float bf2f(u16 h) {
    union { unsigned u; float f; } un; un.u = ((unsigned)h) << 16; return un.f;
}
__device__ __forceinline__ u16 f2bf(float f) {
    union { float f; unsigned u; } un; un.f = f;
    unsigned u = un.u;
    u += 0x7fffu + ((u >> 16) & 1u);   // RNE
    return (u16)(u >> 16);
}

// async global->LDS, 16B per lane, dest = wave-uniform base + lane*16
__device__ __forceinline__ void gload16(const u16* g, u16* l) {
    __builtin_amdgcn_global_load_lds(
        (const __attribute__((address_space(1))) void*)g,
        (__attribute__((address_space(3))) void*)l, 16, 0, 0);
}

// ---------------------------------------------------------------------------
// Embedding kernels -> bf16
// ---------------------------------------------------------------------------
__device__ __forceinline__ float pos_enc(int pos, int c) {
    int i2 = c & ~1;
    float div = expf(-(float)i2 * (9.210340371976184f / 512.0f));
    float arg = (float)pos * div;
    return (c & 1) ? cosf(arg) : sinf(arg);
}

__global__ __launch_bounds__(256) void embed_src_kernel(
    const float* __restrict__ x, const float* __restrict__ w,
    const float* __restrict__ b, u16* __restrict__ h)
{
    int idx = blockIdx.x * 256 + threadIdx.x;
    if (idx >= B_ * S_ * D_) return;
    int c  = idx & (D_ - 1);
    int bs = idx >> 9;
    int s  = bs & (S_ - 1);
    float x0 = x[bs * 2 + 0];
    float x1 = x[bs * 2 + 1];
    h[idx] = f2bf(x0 * w[c] + x1 * w[D_ + c] + b[c] + pos_enc(s, c));
}

__global__ __launch_bounds__(256) void embed_tgt_kernel(
    const float* __restrict__ y, const float* __restrict__ w,
    const float* __restrict__ b, u16* __restrict__ d)
{
    int idx = blockIdx.x * 256 + threadIdx.x;
    if (idx >= B_ * T_ * D_) return;
    int c  = idx & (D_ - 1);
    int bt = idx >> 9;
    int t  = bt % T_;
    int bb = bt / T_;
    float tv = (t == 0) ? 0.0f : y[bb * T_ + (t - 1)];
    d[idx] = f2bf(tv * w[c] + b[c] + pos_enc(t, c));
}

// ---------------------------------------------------------------------------
// Weight convert+transpose: W[K,N] fp32 -> Wt[N,K] bf16. blockIdx.z = matrix.
// ---------------------------------------------------------------------------
__global__ __launch_bounds__(256) void wconv_kernel(
    const float* __restrict__ W, u16* __restrict__ Wt, int K, int N)
{
    __shared__ float tile[32][33];
    size_t mat = (size_t)blockIdx.z * K * N;
    const float* Wm = W + mat;
    u16* Wtm = Wt + mat;
    int n0 = blockIdx.x * 32, k0 = blockIdx.y * 32;
    int tx = threadIdx.x & 31, ty = threadIdx.x >> 5;   // ty 0..7
#pragma unroll
    for (int i = 0; i < 32; i += 8)
        tile[ty + i][tx] = Wm[(size_t)(k0 + ty + i) * N + n0 + tx];
    __syncthreads();
#pragma unroll
    for (int i = 0; i < 32; i += 8)
        Wtm[(size_t)(n0 + ty + i) * K + k0 + tx] = f2bf(tile[tx][ty + i]);
}

// ---------------------------------------------------------------------------
// bf16 MFMA GEMM: C[M,N] = act(A[M,K](lda) @ Wt[N,K]^T + bias), bf16 io,
// fp32 acc. 128x128 tile, BK=64 (two 32-halves per barrier pair), 256 thr
// (4 waves, 2x2 of 64x64 quadrants). M,N mult of 128; K mult of 64.
// ---------------------------------------------------------------------------
__global__ __launch_bounds__(256) void gemm_bf16_kernel(
    const u16* __restrict__ A, int lda, const u16* __restrict__ Bt,
    const float* __restrict__ bias, u16* __restrict__ C, int ldc,
    int M, int N, int K, int relu)
{
    // As/Bs: 2 halves x (128 rows x 32 k) = 8192 u16 each. epi aliases all.
    __shared__ u16 smem[18432];
    u16* As = smem;            // halves at 0, 4096
    u16* Bs = smem + 8192;     // halves at 8192, 12288

    int tid  = threadIdx.x;
    int w    = tid >> 6;
    int lane = tid & 63;
    int m0 = blockIdx.y << 7, n0 = blockIdx.x << 7;

    int sr = w * 32 + (lane >> 2);
    int sk = (lane & 3) * 8;
    const u16* ag0 = A  + (size_t)(m0 + sr)      * lda + sk;
    const u16* ag1 = A  + (size_t)(m0 + sr + 16) * lda + sk;
    const u16* bg0 = Bt + (size_t)(n0 + sr)      * K + sk;
    const u16* bg1 = Bt + (size_t)(n0 + sr + 16) * K + sk;
    u16* al0 = As + (w * 2 + 0) * 512;
    u16* al1 = As + (w * 2 + 1) * 512;
    u16* bl0 = Bs + (w * 2 + 0) * 512;
    u16* bl1 = Bs + (w * 2 + 1) * 512;

    int wm = (w >> 1) * 64, wn = (w & 1) * 64;
    int fr = lane & 15;
    int fk = (lane >> 4) * 8;

    floatx4 acc[4][4] = {};

    for (int k0 = 0; k0 < K; k0 += 64) {
#pragma unroll
        for (int hh = 0; hh < 2; ++hh) {
            int go = k0 + hh * 32;
            int lo = hh * 4096;
            gload16(ag0 + go, al0 + lo);
            gload16(ag1 + go, al1 + lo);
            gload16(bg0 + go, bl0 + lo);
            gload16(bg1 + go, bl1 + lo);
        }
        __syncthreads();

#pragma unroll
        for (int hh = 0; hh < 2; ++hh) {
            int lo = hh * 4096;
            short8 af[4], bf[4];
#pragma unroll
            for (int i = 0; i < 4; ++i)
                af[i] = *(const short8*)&As[lo + (wm + i * 16 + fr) * 32 + fk];
#pragma unroll
            for (int j = 0; j < 4; ++j)
                bf[j] = *(const short8*)&Bs[lo + (wn + j * 16 + fr) * 32 + fk];
#pragma unroll
            for (int i = 0; i < 4; ++i)
#pragma unroll
                for (int j = 0; j < 4; ++j)
                    acc[i][j] = __builtin_amdgcn_mfma_f32_16x16x32_bf16(
                        af[i], bf[j], acc[i][j], 0, 0, 0);
        }
        __syncthreads();
    }

    // epilogue: bias+relu+bf16, bounce through LDS for coalesced stores.
    u16* epi = smem + w * 4608;        // 64 rows x 72 u16 stride
    int cc = lane & 15;
    int rq = (lane >> 4) * 4;
#pragma unroll
    for (int j = 0; j < 4; ++j) {
        float bj = bias[n0 + wn + j * 16 + cc];
#pragma unroll
        for (int i = 0; i < 4; ++i) {
#pragma unroll
            for (int r = 0; r < 4; ++r) {
                float vv = acc[i][j][r] + bj;
                if (relu) vv = fmaxf(vv, 0.f);
                epi[(i * 16 + rq + r) * 72 + j * 16 + cc] = f2bf(vv);
            }
        }
    }
    __syncthreads();
#pragma unroll
    for (int t = 0; t < 8; ++t) {
        int er = t * 8 + (lane >> 3);
        int ec = (lane & 7) * 8;
        short8 vv = *(const short8*)&epi[er * 72 + ec];
        *(short8*)&C[(size_t)(m0 + wm + er) * ldc + n0 + wn + ec] = vv;
    }
}

// ---------------------------------------------------------------------------
// Transposed-output GEMM for V projections: Ct[b][n][s] = A[M,K]@Wt^T + bias,
// M = B*512 (batch-major tokens, S=512), N mult of 128, K mult of 64.
// Same K-loop as gemm_bf16_kernel; epilogue writes C^T per batch.
// ---------------------------------------------------------------------------
__global__ __launch_bounds__(256) void gemm_bf16_t_kernel(
    const u16* __restrict__ A, int lda, const u16* __restrict__ Bt,
    const float* __restrict__ bias, u16* __restrict__ Ct,
    int M, int N, int K)
{
    __shared__ u16 smem[17408];
    u16* As = smem;            // halves at 0, 4096
    u16* Bs = smem + 8192;     // halves at 8192, 12288

    int tid  = threadIdx.x;
    int w    = tid >> 6;
    int lane = tid & 63;
    int m0 = blockIdx.y << 7, n0 = blockIdx.x << 7;

    int sr = w * 32 + (lane >> 2);
    int sk = (lane & 3) * 8;
    const u16* ag0 = A  + (size_t)(m0 + sr)      * lda + sk;
    const u16* ag1 = A  + (size_t)(m0 + sr + 16) * lda + sk;
    const u16* bg0 = Bt + (size_t)(n0 + sr)      * K + sk;
    const u16* bg1 = Bt + (size_t)(n0 + sr + 16) * K + sk;
    u16* al0 = As + (w * 2 + 0) * 512;
    u16* al1 = As + (w * 2 + 1) * 512;
    u16* bl0 = Bs + (w * 2 + 0) * 512;
    u16* bl1 = Bs + (w * 2 + 1) * 512;

    int wm = (w >> 1) * 64, wn = (w & 1) * 64;
    int fr = lane & 15;
    int fk = (lane >> 4) * 8;

    floatx4 acc[4][4] = {};

    for (int k0 = 0; k0 < K; k0 += 64) {
#pragma unroll
        for (int hh = 0; hh < 2; ++hh) {
            int go = k0 + hh * 32;
            int lo = hh * 4096;
            gload16(ag0 + go, al0 + lo);
            gload16(ag1 + go, al1 + lo);
            gload16(bg0 + go, bl0 + lo);
            gload16(bg1 + go, bl1 + lo);
        }
        __syncthreads();

#pragma unroll
        for (int hh = 0; hh < 2; ++hh) {
            int lo = hh * 4096;
            short8 af[4], bf[4];
#pragma unroll
            for (int i = 0; i < 4; ++i)
                af[i] = *(const short8*)&As[lo + (wm + i * 16 + fr) * 32 + fk];
#pragma unroll
            for (int j = 0; j < 4; ++j)
                bf[j] = *(const short8*)&Bs[lo + (wn + j * 16 + fr) * 32 + fk];
#pragma unroll
            for (int i = 0; i < 4; ++i)
#pragma unroll
                for (int j = 0; j < 4; ++j)
                    acc[i][j] = __builtin_amdgcn_mfma_f32_16x16x32_bf16(
                        af[i], bf[j], acc[i][j], 0, 0, 0);
        }
        __syncthreads();
    }

    // transposed epilogue: epi_t[col][row], stride 136; b64 packed writes.
    u16* epi = smem;                   // 128 x 136 = 17408 u16
    int cc = lane & 15;
    int rq = (lane >> 4) * 4;
#pragma unroll
    for (int j = 0; j < 4; ++j) {
        float bj = bias[n0 + wn + j * 16 + cc];
#pragma unroll
        for (int i = 0; i < 4; ++i) {
            unsigned lo = (unsigned)f2bf(acc[i][j][0] + bj) |
                          ((unsigned)f2bf(acc[i][j][1] + bj) << 16);
            unsigned hi = (unsigned)f2bf(acc[i][j][2] + bj) |
                          ((unsigned)f2bf(acc[i][j][3] + bj) << 16);
            *(uint2*)&epi[(size_t)(wn + j * 16 + cc) * 136 + wm + i * 16 + rq] =
                make_uint2(lo, hi);
        }
    }
    __syncthreads();
    int bb2 = m0 >> 9;                 // batch (512 tokens each)
    int s0  = m0 & 511;
#pragma unroll
    for (int tt = 0; tt < 8; ++tt) {
        int dloc = tt * 16 + (tid >> 4);
        int sloc = (tid & 15) * 8;
        short8 vv = *(const short8*)&epi[dloc * 136 + sloc];
        *(short8*)&Ct[(size_t)bb2 * N * 512 + (size_t)(n0 + dloc) * 512 + s0 + sloc] = vv;
    }
}

#define CEXP 0.1803368801111244f   // 0.125 * log2(e)

// ---------------------------------------------------------------------------
// attn2: MFMA flash attention for NON-CAUSAL, Sk = 512 (mult of 64), with V
// pre-transposed in global (Vt[b][D][Sk]). bf16 io, fp32 softmax/acc.
// IN-PLACE capable (O aliases Q slice). Grid = (b*H, q-tile).
// Block = 64 q-rows: 4 waves x 16 q. V^T staged b128->b128 with XOR-8 swizzle.
// ---------------------------------------------------------------------------
__global__ __launch_bounds__(256) void attn2_kernel(
    const u16* Q, int qs, const u16* __restrict__ K, int ks,
    const u16* __restrict__ Vt, u16* O, int Sq, int Sk)
{
    __shared__ u16 Qs[64 * 72];      // [qrow][d], stride 72
    __shared__ u16 Ks[64 * 72];      // [key][d]
    __shared__ u16 Vs[64 * 64];      // [d][k-group^ (d&7)], swizzled
    __shared__ u16 Ps[4][16 * 72];   // per-wave P tile [q][key]

    int tid  = threadIdx.x;
    int w    = tid >> 6;
    int lane = tid & 63;
    int n    = lane & 15;
    int quad = lane >> 4;
    int bh = blockIdx.x;
    int bb = bh >> 3, hhd = bh & 7;
    int q0 = blockIdx.y * 64;

    const u16* Qb = Q  + (size_t)bb * Sq * qs + hhd * DH_;
    const u16* Kb = K  + (size_t)bb * Sk * ks + hhd * DH_;
    const u16* Vb = Vt + ((size_t)bb * D_ + hhd * DH_) * Sk;

    // ---- stage Q once ----
#pragma unroll
    for (int it = 0; it < 2; ++it) {
        int idx = it * 256 + tid;
        int r = idx >> 3, dg = (idx & 7) * 8;
        int qg = q0 + r;
        short8 vv = {};
        if (qg < Sq) vv = *(const short8*)&Qb[(size_t)qg * qs + dg];
        *(short8*)&Qs[r * 72 + dg] = vv;
    }

    float m_i[4], l_i[4];
    floatx4 o_acc[4] = {};
#pragma unroll
    for (int r = 0; r < 4; ++r) { m_i[r] = -1e30f; l_i[r] = 0.f; }
    __syncthreads();

    for (int k0 = 0; k0 < Sk; k0 += 64) {
        // ---- stage K row-major; V^T b128 with XOR swizzle ----
#pragma unroll
        for (int it = 0; it < 2; ++it) {
            int idx = it * 256 + tid;
            int r = idx >> 3, dg = (idx & 7) * 8;
            short8 kv = *(const short8*)&Kb[(size_t)(k0 + r) * ks + dg];
            *(short8*)&Ks[r * 72 + dg] = kv;
            // reuse idx for V: d = idx>>3, k8 = idx&7
            short8 vv = *(const short8*)&Vb[(size_t)r * Sk + k0 + (idx & 7) * 8];
            *(short8*)&Vs[r * 64 + (((idx & 7) ^ (r & 7)) * 8)] = vv;
        }
        __syncthreads();

        // ---- QK^T: 16q x 64k in C-layout frags ----
        floatx4 sc[4] = {};
        short8 aq0 = *(const short8*)&Qs[(w * 16 + n) * 72 + quad * 8];
        short8 aq1 = *(const short8*)&Qs[(w * 16 + n) * 72 + 32 + quad * 8];
#pragma unroll
        for (int j = 0; j < 4; ++j) {
            short8 bk0 = *(const short8*)&Ks[(j * 16 + n) * 72 + quad * 8];
            short8 bk1 = *(const short8*)&Ks[(j * 16 + n) * 72 + 32 + quad * 8];
            sc[j] = __builtin_amdgcn_mfma_f32_16x16x32_bf16(aq0, bk0, sc[j], 0, 0, 0);
            sc[j] = __builtin_amdgcn_mfma_f32_16x16x32_bf16(aq1, bk1, sc[j], 0, 0, 0);
        }

        // ---- online softmax: p = exp2((s - m) * CEXP) ----
#pragma unroll
        for (int r = 0; r < 4; ++r) {
            float mx = fmaxf(fmaxf(sc[0][r], sc[1][r]), fmaxf(sc[2][r], sc[3][r]));
#pragma unroll
            for (int off = 8; off > 0; off >>= 1)
                mx = fmaxf(mx, __shfl_xor(mx, off, 16));
            float mnew = fmaxf(m_i[r], mx);
            float alpha = exp2f((m_i[r] - mnew) * CEXP);
            m_i[r] = mnew;
            float ps = 0.f;
#pragma unroll
            for (int j = 0; j < 4; ++j) {
                float p = exp2f((sc[j][r] - mnew) * CEXP);
                sc[j][r] = p; ps += p;
            }
#pragma unroll
            for (int off = 8; off > 0; off >>= 1)
                ps += __shfl_xor(ps, off, 16);
            l_i[r] = l_i[r] * alpha + ps;
#pragma unroll
            for (int jb = 0; jb < 4; ++jb) o_acc[jb][r] *= alpha;
        }

        // ---- P: C-layout regs -> per-wave LDS [q][key] ----
#pragma unroll
        for (int j = 0; j < 4; ++j)
#pragma unroll
            for (int r = 0; r < 4; ++r)
                Ps[w][(quad * 4 + r) * 72 + j * 16 + n] = f2bf(sc[j][r]);

        // ---- PV: A = P (LDS), B = V^T (swizzled) ----
        short8 ap0 = *(const short8*)&Ps[w][n * 72 + quad * 8];
        short8 ap1 = *(const short8*)&Ps[w][n * 72 + 32 + quad * 8];
#pragma unroll
        for (int jb = 0; jb < 4; ++jb) {
            int d = jb * 16 + n;
            int sw = d & 7;
            short8 bv0 = *(const short8*)&Vs[d * 64 + ((quad ^ sw) * 8)];
            short8 bv1 = *(const short8*)&Vs[d * 64 + (((quad + 4) ^ sw) * 8)];
            o_acc[jb] = __builtin_amdgcn_mfma_f32_16x16x32_bf16(ap0, bv0, o_acc[jb], 0, 0, 0);
            o_acc[jb] = __builtin_amdgcn_mfma_f32_16x16x32_bf16(ap1, bv1, o_acc[jb], 0, 0, 0);
        }
        __syncthreads();
    }

    // ---- output ----
    int qrow0 = q0 + w * 16 + quad * 4;
    float inv[4];
#pragma unroll
    for (int r = 0; r < 4; ++r) inv[r] = 1.0f / l_i[r];
    u16* Ob = O + (size_t)bb * Sq * qs + hhd * DH_;
#pragma unroll
    for (int r = 0; r < 4; ++r) {
        int qg = qrow0 + r;
        if (qg < Sq) {
#pragma unroll
            for (int jb = 0; jb < 4; ++jb)
                Ob[(size_t)qg * qs + jb * 16 + n] = f2bf(o_acc[jb][r] * inv[r]);
        }
    }
}

// ---------------------------------------------------------------------------
// Old MFMA flash attention (causal-capable, in-kernel V transpose) — used for
// decoder self-attention only (Sk = 180, small).
// ---------------------------------------------------------------------------
__global__ __launch_bounds__(256) void attn_mfma_kernel(
    const u16* Q, int qs, const u16* __restrict__ K, int ks,
    const u16* __restrict__ V, u16* O,
    int Sq, int Sk, int causal)
{
    __shared__ u16 Qs[64 * 72];
    __shared__ u16 Ks[64 * 72];
    __shared__ u16 Vt[64 * 72];
    __shared__ u16 Ps[4][16 * 72];

    int tid  = threadIdx.x;
    int w    = tid >> 6;
    int lane = tid & 63;
    int n    = lane & 15;
    int quad = lane >> 4;
    int bh = blockIdx.x;
    int bb = bh >> 3, hhd = bh & 7;
    int q0 = blockIdx.y * 64;

    const u16* Qb = Q + (size_t)bb * Sq * qs + hhd * DH_;
    const u16* Kb = K + (size_t)bb * Sk * ks + hhd * DH_;
    const u16* Vb = V + (size_t)bb * Sk * ks + hhd * DH_;

#pragma unroll
    for (int it = 0; it < 2; ++it) {
        int idx = it * 256 + tid;
        int r = idx >> 3, dg = (idx & 7) * 8;
        int qg = q0 + r;
        short8 vv = {};
        if (qg < Sq) vv = *(const short8*)&Qb[(size_t)qg * qs + dg];
        *(short8*)&Qs[r * 72 + dg] = vv;
    }

    float m_i[4], l_i[4];
    floatx4 o_acc[4] = {};
#pragma unroll
    for (int r = 0; r < 4; ++r) { m_i[r] = -1e30f; l_i[r] = 0.f; }

    int qrow0 = q0 + w * 16 + quad * 4;
    int kend = causal ? ((Sk < q0 + 64) ? Sk : (q0 + 64)) : Sk;
    __syncthreads();

    for (int k0 = 0; k0 < kend; k0 += 64) {
#pragma unroll
        for (int it = 0; it < 2; ++it) {
            int idx = it * 256 + tid;
            int r = idx >> 3, dg = (idx & 7) * 8;
            int kg = k0 + r;
            short8 kv = {}, vv = {};
            if (kg < Sk) {
                kv = *(const short8*)&Kb[(size_t)kg * ks + dg];
                vv = *(const short8*)&Vb[(size_t)kg * ks + dg];
            }
            *(short8*)&Ks[r * 72 + dg] = kv;
            int col = (r + dg) & 63;
#pragma unroll
            for (int j = 0; j < 8; ++j)
                Vt[(dg + j) * 72 + col] = (u16)vv[j];
        }
        __syncthreads();

        floatx4 sc[4] = {};
        short8 aq0 = *(const short8*)&Qs[(w * 16 + n) * 72 + quad * 8];
        short8 aq1 = *(const short8*)&Qs[(w * 16 + n) * 72 + 32 + quad * 8];
#pragma unroll
        for (int j = 0; j < 4; ++j) {
            short8 bk0 = *(const short8*)&Ks[(j * 16 + n) * 72 + quad * 8];
            short8 bk1 = *(const short8*)&Ks[(j * 16 + n) * 72 + 32 + quad * 8];
            sc[j] = __builtin_amdgcn_mfma_f32_16x16x32_bf16(aq0, bk0, sc[j], 0, 0, 0);
            sc[j] = __builtin_amdgcn_mfma_f32_16x16x32_bf16(aq1, bk1, sc[j], 0, 0, 0);
        }

        bool need_mask = (k0 + 64 > Sk) ||
                         (causal && (k0 + 63 > q0 + w * 16));
        if (need_mask) {
#pragma unroll
            for (int j = 0; j < 4; ++j) {
                int kg = k0 + j * 16 + n;
#pragma unroll
                for (int r = 0; r < 4; ++r) {
                    if (kg >= Sk || (causal && kg > qrow0 + r))
                        sc[j][r] = -1e30f;
                }
            }
        }

#pragma unroll
        for (int r = 0; r < 4; ++r) {
            float mx = fmaxf(fmaxf(sc[0][r], sc[1][r]), fmaxf(sc[2][r], sc[3][r]));
#pragma unroll
            for (int off = 8; off > 0; off >>= 1)
                mx = fmaxf(mx, __shfl_xor(mx, off, 16));
            float mnew = fmaxf(m_i[r], mx);
            float alpha = exp2f((m_i[r] - mnew) * CEXP);
            m_i[r] = mnew;
            float ps = 0.f;
#pragma unroll
            for (int j = 0; j < 4; ++j) {
                float p = exp2f((sc[j][r] - mnew) * CEXP);
                sc[j][r] = p; ps += p;
            }
#pragma unroll
            for (int off = 8; off > 0; off >>= 1)
                ps += __shfl_xor(ps, off, 16);
            l_i[r] = l_i[r] * alpha + ps;
#pragma unroll
            for (int jb = 0; jb < 4; ++jb) o_acc[jb][r] *= alpha;
        }

#pragma unroll
        for (int j = 0; j < 4; ++j)
#pragma unroll
            for (int r = 0; r < 4; ++r)
                Ps[w][(quad * 4 + r) * 72 + j * 16 + n] = f2bf(sc[j][r]);

        short8 ap0 = *(const short8*)&Ps[w][n * 72 + quad * 8];
        short8 ap1 = *(const short8*)&Ps[w][n * 72 + 32 + quad * 8];
#pragma unroll
        for (int jb = 0; jb < 4; ++jb) {
            int d = jb * 16 + n;
            int rot = d & ~7;
            short8 bv0 = *(const short8*)&Vt[d * 72 + ((quad * 8 + rot) & 63)];
            short8 bv1 = *(const short8*)&Vt[d * 72 + ((32 + quad * 8 + rot) & 63)];
            o_acc[jb] = __builtin_amdgcn_mfma_f32_16x16x32_bf16(ap0, bv0, o_acc[jb], 0, 0, 0);
            o_acc[jb] = __builtin_amdgcn_mfma_f32_16x16x32_bf16(ap1, bv1, o_acc[jb], 0, 0, 0);
        }
        __syncthreads();
    }

    float inv[4];
#pragma unroll
    for (int r = 0; r < 4; ++r) inv[r] = 1.0f / l_i[r];
    u16* Ob = O + (size_t)bb * Sq * qs + hhd * DH_;
#pragma unroll
    for (int r = 0; r < 4; ++r) {
        int qg = qrow0 + r;
        if (qg < Sq) {
#pragma unroll
            for (int jb = 0; jb < 4; ++jb)
                Ob[(size_t)qg * qs + jb * 16 + n] = f2bf(o_acc[jb][r] * inv[r]);
        }
    }
}

// ---------------------------------------------------------------------------
// h[row,:] = LN(h[row,:] + delta[row,:]) * scale + bias (bf16 io, fp32 math)
// ---------------------------------------------------------------------------
__global__ __launch_bounds__(128) void add_ln_kernel(
    u16* __restrict__ h, const u16* __restrict__ delta,
    const float* __restrict__ scale, const float* __restrict__ bias)
{
    __shared__ float red[2][2];
    int row = blockIdx.x, tid = threadIdx.x;
    int lane = tid & 63, wv = tid >> 6;
    size_t base = (size_t)row * D_ + tid * 4;
    uint2 hv = *(const uint2*)&h[base];
    uint2 dv = *(const uint2*)&delta[base];
    float v0 = bf2f(hv.x & 0xffff) + bf2f(dv.x & 0xffff);
    float v1 = bf2f(hv.x >> 16)    + bf2f(dv.x >> 16);
    float v2 = bf2f(hv.y & 0xffff) + bf2f(dv.y & 0xffff);
    float v3 = bf2f(hv.y >> 16)    + bf2f(dv.y >> 16);

    float a  = v0 + v1 + v2 + v3;
    float b2 = v0 * v0 + v1 * v1 + v2 * v2 + v3 * v3;
#pragma unroll
    for (int off = 32; off > 0; off >>= 1) {
        a  += __shfl_xor(a, off);
        b2 += __shfl_xor(b2, off);
    }
    if (lane == 0) { red[wv][0] = a; red[wv][1] = b2; }
    __syncthreads();
    float S1 = red[0][0] + red[1][0];
    float S2 = red[0][1] + red[1][1];
    float mu = S1 * (1.0f / 512.0f);
    float var = S2 * (1.0f / 512.0f) - mu * mu;
    float rs = rsqrtf(var + 1e-5f);

    int c = tid * 4;
    float4 sc = *(const float4*)&scale[c];
    float4 bi = *(const float4*)&bias[c];
    unsigned lo = (unsigned)f2bf((v0 - mu) * rs * sc.x + bi.x) |
                  ((unsigned)f2bf((v1 - mu) * rs * sc.y + bi.y) << 16);
    unsigned hi = (unsigned)f2bf((v2 - mu) * rs * sc.z + bi.z) |
                  ((unsigned)f2bf((v3 - mu) * rs * sc.w + bi.w) << 16);
    *(uint2*)&h[base] = make_uint2(lo, hi);
}

// ---------------------------------------------------------------------------
// out[row] = d[row,:] . w[:] + b   (one wave per row; d bf16, out fp32)
// ---------------------------------------------------------------------------
__global__ __launch_bounds__(64) void out_proj_kernel(
    const u16* __restrict__ d, const float* __restrict__ w,
    const float* __restrict__ b, float* __restrict__ out)
{
    int row = blockIdx.x, lane = threadIdx.x;
    float s = 0.f;
    for (int c = lane; c < D_; c += 64) s += bf2f(d[(size_t)row * D_ + c]) * w[c];
#pragma unroll
    for (int off = 32; off > 0; off >>= 1) s += __shfl_down(s, off);
    if (lane == 0) out[row] = s + b[0];
}

// ---------------------------------------------------------------------------
// Host orchestration
// ---------------------------------------------------------------------------
extern "C" void kernel_launch(void* const* d_in, const int* in_sizes, int n_in,
                              void* d_out, int out_size, void* d_ws, size_t ws_size,
                              hipStream_t stream)
{
    const float* x          = (const float*)d_in[0];
    const float* y          = (const float*)d_in[1];
    const float* src_w      = (const float*)d_in[2];
    const float* src_b      = (const float*)d_in[3];
    const float* tgt_w      = (const float*)d_in[4];
    const float* tgt_b      = (const float*)d_in[5];
    const float* enc_attn_w = (const float*)d_in[6];
    const float* enc_attn_b = (const float*)d_in[7];
    const float* enc_ffn_w1 = (const float*)d_in[8];
    const float* enc_ffn_b1 = (const float*)d_in[9];
    const float* enc_ffn_w2 = (const float*)d_in[10];
    const float* enc_ffn_b2 = (const float*)d_in[11];
    const float* enc_ln_s   = (const float*)d_in[12];
    const float* enc_ln_b   = (const float*)d_in[13];
    const float* dec_self_w = (const float*)d_in[14];
    const float* dec_self_b = (const float*)d_in[15];
    const float* dec_cross_w= (const float*)d_in[16];
    const float* dec_cross_b= (const float*)d_in[17];
    const float* dec_ffn_w1 = (const float*)d_in[18];
    const float* dec_ffn_b1 = (const float*)d_in[19];
    const float* dec_ffn_w2 = (const float*)d_in[20];
    const float* dec_ffn_b2 = (const float*)d_in[21];
    const float* dec_ln_s   = (const float*)d_in[22];
    const float* dec_ln_b   = (const float*)d_in[23];
    const float* out_w      = (const float*)d_in[24];
    const float* out_b      = (const float*)d_in[25];
    float* out = (float*)d_out;

    // Workspace (u16). Total = 49,086,464 u16 = 98.2 MB (same as before).
    const size_t E_BSD = (size_t)B_ * S_ * D_;    // 8,388,608
    const size_t E_BTD = (size_t)B_ * T_ * D_;    // 2,949,120
    const size_t WDD   = (size_t)D_ * D_;         // 262,144
    const size_t WDF   = (size_t)D_ * F_;         // 1,048,576
    const int MS = B_ * S_;   // 16384
    const int MT = B_ * T_;   // 5760

    u16* h    = (u16*)d_ws;                  // encoder state -> memory
    u16* qk   = h + E_BSD;                   // 16.8M region: enc QK / dec QKV /
                                             //   FFN mid / cross ck+cq
    u16* o    = qk + (size_t)MS * 1024;      // [MS,512] proj/FFN output
    u16* dbuf = o + E_BSD;                   // decoder state
    u16* wsc  = dbuf + E_BTD;                // weight scratch (4.2M)
    u16* vt   = wsc + 8 * WDD + 2 * WDF;     // V^T [B,512,512] (8.4M)
    // aliases into qk region (dead when used):
    u16* mid  = qk;                          // FFN hidden (<= 8192x2048)
    u16* ck   = qk;                          // cross-attn K [MS,512]
    u16* cq   = qk + E_BSD;                  // cross-attn Q [MT,512]

    auto gemm = [&](const u16* A, int lda, const u16* Wt, const float* bi,
                    u16* C, int ldc, int M, int N, int K, int relu) {
        dim3 g(N / 128, M / 128);
        gemm_bf16_kernel<<<g, dim3(256), 0, stream>>>(A, lda, Wt, bi, C, ldc,
                                                      M, N, K, relu);
    };
    auto gemm_t = [&](const u16* A, int lda, const u16* Wt, const float* bi,
                      u16* Ct, int M, int N, int K) {
        dim3 g(N / 128, M / 128);
        gemm_bf16_t_kernel<<<g, dim3(256), 0, stream>>>(A, lda, Wt, bi, Ct, M, N, K);
    };
    auto attn2 = [&](const u16* Qp, int qs, const u16* Kp, int ks,
                     const u16* Vtp, u16* Op, int Sq, int Sk) {
        dim3 g(B_ * H_, (Sq + 63) / 64);
        attn2_kernel<<<g, dim3(256), 0, stream>>>(Qp, qs, Kp, ks, Vtp, Op, Sq, Sk);
    };
    auto attn_old = [&](const u16* Qp, int qs, const u16* Kp, int ks,
                        const u16* Vp, u16* Op, int Sq, int Sk, int causal) {
        dim3 g(B_ * H_, (Sq + 63) / 64);
        attn_mfma_kernel<<<g, dim3(256), 0, stream>>>(Qp, qs, Kp, ks, Vp, Op,
                                                      Sq, Sk, causal);
    };
    auto addln = [&](u16* hp, const u16* dp, const float* sc, const float* bi,
                     int rows) {
        add_ln_kernel<<<dim3(rows), dim3(128), 0, stream>>>(hp, dp, sc, bi);
    };
    auto wconv = [&](const float* W, u16* Wt, int K, int N, int nmat) {
        wconv_kernel<<<dim3(N / 32, K / 32, nmat), dim3(256), 0, stream>>>(W, Wt, K, N);
    };

    // ---- encoder ----
    embed_src_kernel<<<dim3((B_ * S_ * D_ + 255) / 256), dim3(256), 0, stream>>>(
        x, src_w, src_b, h);
    for (int l = 0; l < L_; ++l) {
        wconv(enc_attn_w + (size_t)l * 4 * WDD, wsc, D_, D_, 4);   // q,k,v,o
        wconv(enc_ffn_w1 + (size_t)l * WDF, wsc + 4 * WDD, D_, F_, 1);
        wconv(enc_ffn_w2 + (size_t)l * WDF, wsc + 4 * WDD + WDF, F_, D_, 1);

        const float* bl = enc_attn_b + (size_t)l * 4 * D_;
        // QK fused (N=1024) + V transposed
        gemm(h, D_, wsc, bl, qk, 1024, MS, 1024, D_, 0);
        gemm_t(h, D_, wsc + 2 * WDD, bl + 2 * D_, vt, MS, D_, D_);
        attn2(qk, 1024, qk + 512, 1024, vt, qk, S_, S_);          // in-place
        gemm(qk, 1024, wsc + 3 * WDD, bl + 3 * D_, o, D_, MS, D_, D_, 0);
        addln(h, o, enc_ln_s + (size_t)l * 2 * D_, enc_ln_b + (size_t)l * 2 * D_, MS);

        // FFN, chunked by 8192 rows (mid aliases dead qk region)
        for (int m0 = 0; m0 < MS; m0 += 8192) {
            gemm(h + (size_t)m0 * D_, D_, wsc + 4 * WDD,
                 enc_ffn_b1 + (size_t)l * F_, mid, F_, 8192, F_, D_, 1);
            gemm(mid, F_, wsc + 4 * WDD + WDF, enc_ffn_b2 + (size_t)l * D_,
                 o + (size_t)m0 * D_, D_, 8192, D_, F_, 0);
        }
        addln(h, o, enc_ln_s + (size_t)l * 2 * D_ + D_,
              enc_ln_b + (size_t)l * 2 * D_ + D_, MS);
    }
    // h == memory from here on.

    // ---- decoder ----
    embed_tgt_kernel<<<dim3((B_ * T_ * D_ + 255) / 256), dim3(256), 0, stream>>>(
        y, tgt_w, tgt_b, dbuf);
    for (int l = 0; l < L_; ++l) {
        wconv(dec_self_w  + (size_t)l * 4 * WDD, wsc, D_, D_, 4);
        wconv(dec_cross_w + (size_t)l * 4 * WDD, wsc + 4 * WDD, D_, D_, 4);
        wconv(dec_ffn_w1  + (size_t)l * WDF, wsc + 8 * WDD, D_, F_, 1);
        wconv(dec_ffn_w2  + (size_t)l * WDF, wsc + 8 * WDD + WDF, F_, D_, 1);

        // self-attention (causal), fused QKV, old kernel
        const float* bl = dec_self_b + (size_t)l * 4 * D_;
        gemm(dbuf, D_, wsc, bl, qk, 1536, MT, 1536, D_, 0);
        attn_old(qk, 1536, qk + 512, 1536, qk + 1024, qk, T_, T_, 1);
        gemm(qk, 1536, wsc + 3 * WDD, bl + 3 * D_, o, D_, MT, D_, D_, 0);
        addln(dbuf, o, dec_ln_s + (size_t)l * 3 * D_,
              dec_ln_b + (size_t)l * 3 * D_, MT);

        // cross-attention: K + V^T over memory, Q over decoder state
        const float* bc = dec_cross_b + (size_t)l * 4 * D_;
        gemm(h, D_, wsc + 5 * WDD, bc + D_, ck, 512, MS, D_, D_, 0);
        gemm_t(h, D_, wsc + 6 * WDD, bc + 2 * D_, vt, MS, D_, D_);
        gemm(dbuf, D_, wsc + 4 * WDD, bc, cq, D_, MT, D_, D_, 0);
        attn2(cq, 512, ck, 512, vt, cq, T_, S_);                  // in-place
        gemm(cq, D_, wsc + 7 * WDD, bc + 3 * D_, o, D_, MT, D_, D_, 0);
        addln(dbuf, o, dec_ln_s + (size_t)l * 3 * D_ + D_,
              dec_ln_b + (size_t)l * 3 * D_ + D_, MT);

        // FFN (single chunk, MT=5760 rows)
        gemm(dbuf, D_, wsc + 8 * WDD, dec_ffn_b1 + (size_t)l * F_,
             mid, F_, MT, F_, D_, 1);
        gemm(mid, F_, wsc + 8 * WDD + WDF, dec_ffn_b2 + (size_t)l * D_,
             o, D_, MT, D_, F_, 0);
        addln(dbuf, o, dec_ln_s + (size_t)l * 3 * D_ + 2 * D_,
              dec_ln_b + (size_t)l * 3 * D_ + 2 * D_, MT);
    }

    out_proj_kernel<<<dim3(MT), dim3(64), 0, stream>>>(dbuf, out_w, out_b, out);
}